// Round 1
// baseline (65187.891 us; speedup 1.0000x reference)
//
#include <hip/hip_runtime.h>
#include <math.h>

#define SEQ 1024
#define BB  64
#define INF 512
#define HH  512

// ---------------------------------------------------------------------------
// P1: h[b,j] = relu( b0[j] + sum_k x[t,b,k]*W0[j,k] + sum_k c[b,k]*W0[j,512+k] )
// Grid: 256 WGs = 8 b-tiles (8 batches each) x 32 j-tiles (16 cols each).
// Thread pair (kh=0: x-part, kh=1: c-part) each does a K=512 dot, combined
// via __shfl_xor(1).
// ---------------------------------------------------------------------------
__global__ __launch_bounds__(256) void dlstm_p1(
    const float* __restrict__ x_all, const float* __restrict__ W0,
    const float* __restrict__ b0, const float* __restrict__ c,
    float* __restrict__ h, int t)
{
    const int wg    = blockIdx.x;
    const int btile = wg >> 5;      // 0..7
    const int jtile = wg & 31;      // 0..31
    const int tl    = threadIdx.x;
    const int o     = tl >> 1;      // 0..127
    const int kh    = tl & 1;       // 0 -> x-part, 1 -> c-part
    const int b     = btile * 8 + (o >> 4);
    const int j     = jtile * 16 + (o & 15);

    const float* __restrict__ A =
        kh ? (c + (size_t)b * HH)
           : (x_all + (size_t)t * BB * INF + (size_t)b * INF);
    const float* __restrict__ W = W0 + (size_t)j * (HH + INF) + kh * INF;

    float acc = 0.f;
    #pragma unroll 8
    for (int k = 0; k < INF; k += 4) {
        const float4 a4 = *reinterpret_cast<const float4*>(A + k);
        const float4 w4 = *reinterpret_cast<const float4*>(W + k);
        acc += a4.x * w4.x + a4.y * w4.y + a4.z * w4.z + a4.w * w4.w;
    }
    const float tot = acc + __shfl_xor(acc, 1);
    if (kh == 0) {
        const float v = tot + b0[j];
        h[(size_t)b * HH + j] = fmaxf(v, 0.f);
    }
}

// ---------------------------------------------------------------------------
// P2: for each (b,j) compute y at rows {j, 512+j, 1024+j, 1536+j} of W1,
// then: new_cx = relu(y_a)-relu(y_b); hx_out = relu(y_h); f = sigmoid(y_f);
//       c_new = f*new_cx + (1-f)*c.
// Thread pair qp=0 handles rows (j, 512+j); qp=1 handles (1024+j, 1536+j).
// Results exchanged via __shfl_xor(1). qp=0 updates c (and final c at t=1023);
// qp=1 writes the timestep output.
// Grid: 256 WGs = 8 b-tiles x 32 j-tiles (16 cols each).
// ---------------------------------------------------------------------------
__global__ __launch_bounds__(256) void dlstm_p2(
    const float* __restrict__ h, const float* __restrict__ W1,
    const float* __restrict__ b1, float* __restrict__ c,
    float* __restrict__ out, float* __restrict__ cfin, int t)
{
    const int wg    = blockIdx.x;
    const int btile = wg >> 5;
    const int jtile = wg & 31;
    const int tl    = threadIdx.x;
    const int o     = tl >> 1;
    const int qp    = tl & 1;
    const int b     = btile * 8 + (o >> 4);
    const int j     = jtile * 16 + (o & 15);

    const float* __restrict__ hb = h + (size_t)b * HH;
    const int q0 = qp * 2, q1 = q0 + 1;
    const float* __restrict__ wr0 = W1 + (size_t)(q0 * HH + j) * HH;
    const float* __restrict__ wr1 = W1 + (size_t)(q1 * HH + j) * HH;

    float a0 = 0.f, a1 = 0.f;
    #pragma unroll 8
    for (int k = 0; k < HH; k += 4) {
        const float4 hv = *reinterpret_cast<const float4*>(hb + k);
        const float4 u  = *reinterpret_cast<const float4*>(wr0 + k);
        const float4 v  = *reinterpret_cast<const float4*>(wr1 + k);
        a0 += hv.x * u.x + hv.y * u.y + hv.z * u.z + hv.w * u.w;
        a1 += hv.x * v.x + hv.y * v.y + hv.z * v.z + hv.w * v.w;
    }
    a0 += b1[q0 * HH + j];
    a1 += b1[q1 * HH + j];

    // exchange with partner lane
    const float p0 = __shfl_xor(a0, 1);   // qp0 receives y_hx ; qp1 receives y_a
    const float p1 = __shfl_xor(a1, 1);   // qp0 receives y_f  ; qp1 receives y_b
    (void)p0;

    if (qp == 0) {
        // a0 = y_cx_a, a1 = y_cx_b, p1 = y_forget
        const float ncx = fmaxf(a0, 0.f) - fmaxf(a1, 0.f);
        const float f   = 1.f / (1.f + expf(-p1));
        const size_t idx = (size_t)b * HH + j;
        const float cn = f * ncx + (1.f - f) * c[idx];
        c[idx] = cn;
        if (t == SEQ - 1) cfin[idx] = cn;
    } else {
        // a0 = y_hx
        out[(size_t)t * BB * HH + (size_t)b * HH + j] = fmaxf(a0, 0.f);
    }
}

// ---------------------------------------------------------------------------
extern "C" void kernel_launch(void* const* d_in, const int* in_sizes, int n_in,
                              void* d_out, int out_size, void* d_ws, size_t ws_size,
                              hipStream_t stream)
{
    const float* x  = (const float*)d_in[0];   // (SEQ, B, IN)
    const float* W0 = (const float*)d_in[1];   // (H, H+IN)
    const float* b0 = (const float*)d_in[2];   // (H)
    const float* W1 = (const float*)d_in[3];   // (4H, H)
    const float* b1 = (const float*)d_in[4];   // (4H)

    float* out  = (float*)d_out;                       // (SEQ, B, H)
    float* cfin = out + (size_t)SEQ * BB * HH;         // (1, B, H)

    float* c = (float*)d_ws;                           // (B, H) state
    float* h = c + (size_t)BB * HH;                    // (B, H) hidden

    // c0 = zeros (d_ws is poisoned before every run)
    hipMemsetAsync(c, 0, (size_t)BB * HH * sizeof(float), stream);

    for (int t = 0; t < SEQ; ++t) {
        dlstm_p1<<<256, 256, 0, stream>>>(x, W0, b0, c, h, t);
        dlstm_p2<<<256, 256, 0, stream>>>(h, W1, b1, c, out, cfin, t);
    }
}

// Round 2
// 23281.561 us; speedup vs baseline: 2.8000x; 2.8000x over previous
//
#include <hip/hip_runtime.h>
#include <math.h>

#define SEQ 1024
#define BB  64
#define INF 512
#define HH  512
#define W0LD 1024          // W0 row stride (HH+INF)
#define TSLICE 32768       // 64*512 elements per t-slice

// ---------------------------------------------------------------------------
// Precompute kernel: xw[t][j][b] = sum_{k<512} x[t][b][k] * W0[j][k]
// (the x-half of layer 0, hoisted out of the sequential loop).
// Output is stored TRANSPOSED per t: xw + t*32768 + j*64 + b, aliased onto
// d_out's t-slice (P1 of step t consumes it, P2 of step t overwrites it).
// Grid: 8192 WGs = 1024 t  x 8 j-tiles(64 j each). 256 threads.
// Tile: 64 b x 64 j, K chunked by 64 through LDS (both operands transposed
// to [k][*] so the inner loop is two ds_read_b128 + 16 FMA per k).
// ---------------------------------------------------------------------------
__global__ __launch_bounds__(256) void xw0_gemm(
    const float* __restrict__ x, const float* __restrict__ W0,
    float* __restrict__ xw)
{
    const int bid = blockIdx.x;
    const int t   = bid >> 3;
    const int jt  = bid & 7;
    const int tid = threadIdx.x;

    __shared__ float xs[64][68];   // [k][b], pad 68 keeps 16B row alignment, 2-way max
    __shared__ float ws[64][68];   // [k][j]

    const int bq = tid & 15;       // b quad
    const int jq = tid >> 4;       // j quad (0..15)
    float acc[4][4];               // [jj][bb]
    #pragma unroll
    for (int i = 0; i < 4; ++i)
        #pragma unroll
        for (int k = 0; k < 4; ++k) acc[i][k] = 0.f;

    // staging mapping: row r = tid>>2 (64 rows), q = tid&3; each thread 4 float4
    const int r = tid >> 2, q = tid & 3;
    const float* xrow = x  + (size_t)t * BB * INF + (size_t)r * INF;
    const float* wrow = W0 + (size_t)(jt * 64 + r) * W0LD;

    for (int kc = 0; kc < 512; kc += 64) {
        #pragma unroll
        for (int u = 0; u < 4; ++u) {
            const int k0 = 4 * q + 16 * u;           // float4 index*4 within chunk
            float4 xv = *reinterpret_cast<const float4*>(xrow + kc + k0);
            xs[k0 + 0][r] = xv.x; xs[k0 + 1][r] = xv.y;
            xs[k0 + 2][r] = xv.z; xs[k0 + 3][r] = xv.w;
            float4 wv = *reinterpret_cast<const float4*>(wrow + kc + k0);
            ws[k0 + 0][r] = wv.x; ws[k0 + 1][r] = wv.y;
            ws[k0 + 2][r] = wv.z; ws[k0 + 3][r] = wv.w;
        }
        __syncthreads();
        #pragma unroll 16
        for (int k = 0; k < 64; ++k) {
            const float4 xv = *reinterpret_cast<const float4*>(&xs[k][bq * 4]);
            const float4 wv = *reinterpret_cast<const float4*>(&ws[k][jq * 4]);
            const float xa[4] = {xv.x, xv.y, xv.z, xv.w};
            const float wa[4] = {wv.x, wv.y, wv.z, wv.w};
            #pragma unroll
            for (int jj = 0; jj < 4; ++jj)
                #pragma unroll
                for (int bb = 0; bb < 4; ++bb)
                    acc[jj][bb] += wa[jj] * xa[bb];
        }
        __syncthreads();
    }

    float* dst = xw + (size_t)t * TSLICE;
    #pragma unroll
    for (int jj = 0; jj < 4; ++jj) {
        const int j = jt * 64 + jq * 4 + jj;
        float4 v = make_float4(acc[jj][0], acc[jj][1], acc[jj][2], acc[jj][3]);
        *reinterpret_cast<float4*>(dst + (size_t)j * 64 + bq * 4) = v;
    }
}

// ---------------------------------------------------------------------------
// P1 (per step): hT[j][b] = relu( xw[t][j][b] + b0[j] + sum_k cT[k][b]*W0[j][512+k] )
// Grid 256 WGs (2 j each), 256 threads: b = tid&63 (coalesced activation dim),
// jl = bit6, kh = bit7 (K-half split, LDS-reduced). Weight row offset is
// wave-uniform -> readfirstlane -> scalar loads.
// ---------------------------------------------------------------------------
__global__ __launch_bounds__(256) void step1(
    const float* __restrict__ W0, const float* __restrict__ b0,
    const float* __restrict__ cT, const float* __restrict__ xw,
    float* __restrict__ hT, int t)
{
    const int jt  = blockIdx.x;
    const int tid = threadIdx.x;
    const int b   = tid & 63;
    const int jl  = (tid >> 6) & 1;
    const int kh  = tid >> 7;
    const int j   = jt * 2 + jl;

    const int woff = __builtin_amdgcn_readfirstlane(j * W0LD + INF + kh * 256);
    const float* __restrict__ wrow = W0 + woff;
    const float* __restrict__ cp   = cT + kh * 256 * 64 + b;

    float acc = 0.f;
    #pragma unroll 8
    for (int k = 0; k < 256; k += 4) {
        const float4 w4 = *reinterpret_cast<const float4*>(wrow + k);
        acc += cp[(k + 0) * 64] * w4.x + cp[(k + 1) * 64] * w4.y +
               cp[(k + 2) * 64] * w4.z + cp[(k + 3) * 64] * w4.w;
    }

    __shared__ float red[128];
    if (kh == 1) red[jl * 64 + b] = acc;
    __syncthreads();
    if (kh == 0) {
        const float tot = acc + red[jl * 64 + b] + b0[j] +
                          xw[(size_t)t * TSLICE + (size_t)j * 64 + b];
        hT[j * 64 + b] = fmaxf(tot, 0.f);
    }
}

// ---------------------------------------------------------------------------
// P2 (per step): y rows {j, 512+j, 1024+j, 1536+j} of W1 against hT, then the
// gate epilogue updates cT and writes out[t] (overwriting the consumed xw[t]).
// Grid 256 WGs (2 j each), 256 threads: b = tid&63, jl = bit6, gh = bit7
// (gh=0 -> gates 0,1 ; gh=1 -> gates 2,3), LDS exchange for the epilogue.
// ---------------------------------------------------------------------------
__global__ __launch_bounds__(256) void step2(
    const float* __restrict__ W1, const float* __restrict__ b1,
    const float* __restrict__ hT, float* __restrict__ cT,
    float* __restrict__ out, int t)
{
    const int jt  = blockIdx.x;
    const int tid = threadIdx.x;
    const int b   = tid & 63;
    const int jl  = (tid >> 6) & 1;
    const int gh  = tid >> 7;
    const int j   = jt * 2 + jl;
    const int g0  = gh * 2, g1 = g0 + 1;

    const int r0 = __builtin_amdgcn_readfirstlane((g0 * HH + j) * HH);
    const int r1 = __builtin_amdgcn_readfirstlane((g1 * HH + j) * HH);
    const float* __restrict__ w0p = W1 + r0;
    const float* __restrict__ w1p = W1 + r1;
    const float* __restrict__ hp  = hT + b;

    float a0 = 0.f, a1 = 0.f;
    #pragma unroll 8
    for (int k = 0; k < 512; k += 4) {
        const float4 u = *reinterpret_cast<const float4*>(w0p + k);
        const float4 v = *reinterpret_cast<const float4*>(w1p + k);
        const float h0 = hp[(k + 0) * 64], h1 = hp[(k + 1) * 64];
        const float h2 = hp[(k + 2) * 64], h3 = hp[(k + 3) * 64];
        a0 += h0 * u.x + h1 * u.y + h2 * u.z + h3 * u.w;
        a1 += h0 * v.x + h1 * v.y + h2 * v.z + h3 * v.w;
    }
    a0 += b1[g0 * HH + j];
    a1 += b1[g1 * HH + j];

    __shared__ float red[2][64][2];
    if (gh == 1) { red[jl][b][0] = a0; red[jl][b][1] = a1; }
    __syncthreads();
    if (gh == 0) {
        const float yh  = red[jl][b][0];          // gate2: new_hx
        const float yf  = red[jl][b][1];          // gate3: forget
        const float ncx = fmaxf(a0, 0.f) - fmaxf(a1, 0.f);  // drelu(gates 0,1)
        const float f   = 1.f / (1.f + expf(-yf));
        const int   idx = j * 64 + b;
        const float cn  = f * ncx + (1.f - f) * cT[idx];
        cT[idx] = cn;
        out[(size_t)t * TSLICE + (size_t)b * HH + j] = fmaxf(yh, 0.f);
        if (t == SEQ - 1)
            out[(size_t)SEQ * TSLICE + (size_t)b * HH + j] = cn;
    }
}

// ---------------------------------------------------------------------------
extern "C" void kernel_launch(void* const* d_in, const int* in_sizes, int n_in,
                              void* d_out, int out_size, void* d_ws, size_t ws_size,
                              hipStream_t stream)
{
    const float* x  = (const float*)d_in[0];   // (SEQ, B, IN)
    const float* W0 = (const float*)d_in[1];   // (H, H+IN)
    const float* b0 = (const float*)d_in[2];   // (H)
    const float* W1 = (const float*)d_in[3];   // (4H, H)
    const float* b1 = (const float*)d_in[4];   // (4H)

    float* out = (float*)d_out;                // (SEQ,B,H) + (1,B,H) tail
    float* cT  = (float*)d_ws;                 // c transposed [k][b], 128KB
    float* hT  = cT + (size_t)HH * BB;         // h transposed [k][b], 128KB

    // c0 = zeros
    hipMemsetAsync(cT, 0, (size_t)HH * BB * sizeof(float), stream);

    // Hoisted x-part of layer 0, written transposed into d_out's t-slices.
    xw0_gemm<<<8192, 256, 0, stream>>>(x, W0, out);

    for (int t = 0; t < SEQ; ++t) {
        step1<<<256, 256, 0, stream>>>(W0, b0, cT, out, hT, t);
        step2<<<256, 256, 0, stream>>>(W1, b1, hT, cT, out, t);
    }
}